// Round 17
// baseline (210.587 us; speedup 1.0000x reference)
//
#include <hip/hip_runtime.h>
#include <math.h>

#define KNN    10
#define NPTS   8192
#define HID    64
#define NF     76
#define Q      16                // queries per wave
#define CAP    64                // pass-2 collection capacity per query
#define F32_INF __uint_as_float(0x7F800000u)

__device__ __forceinline__ float rl(float v, int lane) {
    return __int_as_float(__builtin_amdgcn_readlane(__float_as_int(v), lane));
}

// ---------------------------------------------------------------------------
// Prep: pts4[i] = (x, y, z, x^2+y^2+z^2)  (w chain identical to all rounds).
// ---------------------------------------------------------------------------
__global__ __launch_bounds__(256) void prep_kernel(const float* __restrict__ cloud,
                                                   float4* __restrict__ pts4) {
    const int i = blockIdx.x * 256 + threadIdx.x;      // 0..32767
    const float x = cloud[i * 3 + 0];
    const float y = cloud[i * 3 + 1];
    const float z = cloud[i * 3 + 2];
    pts4[i] = make_float4(x, y, z, fmaf(z, z, fmaf(y, y, x * x)));
}

// ---------------------------------------------------------------------------
// FUSED KNN + FEAT + MLP.
// KNN part: exact R14 scan (validated 113.6us / absmax 4.39e-3): transposed
// scan, folded -2 coords, rank-11 chunk-minima threshold + 1e-3, exact
// R1-chain key rebuild in rare hit branch, top-11 + self-filter.
// Phase 3 writes indices to LDS (global knn_idx round-trip DELETED).
// Then the verbatim R14 4-thr/point feat+MLP body runs on t<128 for the
// block's own 32 points — no separate launch, no gap; latency overlaps the
// other resident blocks' scan phases. W1 read directly from global
// (L1-resident, 4 addr streams/wave) to keep LDS at ~38KB -> 4 blocks/CU,
// preserving 8 waves/SIMD for the scan. All feat math bitwise = R14.
// Block 512 thr = 8 waves = 2 query-groups x 4 candidate-quarters; grid 1024.
// ---------------------------------------------------------------------------
__global__ __launch_bounds__(512) void knn_feat_kernel(const float4* __restrict__ pts4,
                                                       const float* __restrict__ W1,
                                                       const float* __restrict__ b1,
                                                       const float* __restrict__ W2,
                                                       const float* __restrict__ b2,
                                                       float* __restrict__ out) {
    __shared__ unsigned long long coll[CAP][33];   // 16.9 KB
    __shared__ float pk[8][Q][17];                 // 8.7 KB
    __shared__ float tau_s[32];
    __shared__ int   cnt[32];
    __shared__ int   idx_s[32][KNN];               // 1.28 KB (phase3 -> feat)
    __shared__ float fs[32][NF + 1];               // 9.86 KB, stride 77
    __shared__ float b1s[HID];
    __shared__ float w2s[HID * 3];
    __shared__ float b2s[3];

    const int t    = threadIdx.x;
    const int w    = t >> 6;                  // wave 0..7
    const int lane = t & 63;
    const int g    = w >> 2;                  // query group 0..1
    const int h    = w & 3;                   // candidate quarter 0..3
    const int bx   = blockIdx.x;              // 0..1023
    const int b    = bx >> 8;                 // batch
    const int n_base = (bx & 255) * 32 + g * Q;   // batch-local first query of group
    const int lq_base = g * Q;                // block-local query base
    const int cb0 = h * (NPTS / 4);           // candidate base for this wave

    const float4* pb = pts4 + b * NPTS;

    if (t < 32) cnt[t] = 0;                   // visible after barrier 1
    if (t < HID) b1s[t] = b1[t];              // small stages (visible after barrier 1)
    if (t >= 64 && t < 64 + HID * 3) w2s[t - 64] = W2[t - 64];
    if (t >= 256 && t < 259) b2s[t - 256] = b2[t - 256];

    float qxs[Q], qys[Q], qzs[Q], qss[Q];
#pragma unroll
    for (int qq = 0; qq < Q; ++qq) {
        const float4 qv = pb[n_base + qq];
        qxs[qq] = qv.x; qys[qq] = qv.y; qzs[qq] = qv.z; qss[qq] = qv.w;
    }

    // ---------------- pass 1: per-lane minima over this quarter ----------------
    float vmin[Q];
#pragma unroll
    for (int qq = 0; qq < Q; ++qq) vmin[qq] = F32_INF;

    float4 cp = pb[cb0 + lane];               // coalesced vector load
    for (int ti = 0; ti < NPTS / 4 / 64; ++ti) {  // 32 tiles
        const float4 np = (ti < NPTS / 4 / 64 - 1) ? pb[cb0 + (ti + 1) * 64 + lane] : cp;
        const float a2x = -2.0f * cp.x;       // once per tile, amortized /16
        const float a2y = -2.0f * cp.y;
        const float a2z = -2.0f * cp.z;
        const float aw  = cp.w;
#pragma unroll
        for (int qq = 0; qq < Q; ++qq) {
            const float v = fmaf(a2x, qxs[qq], fmaf(a2y, qys[qq], fmaf(a2z, qzs[qq], aw)));
            vmin[qq] = fminf(vmin[qq], v);    // self included (rank arg handles it)
        }
        cp = np;
    }

#pragma unroll
    for (int qq = 0; qq < Q; ++qq) {
        float v = vmin[qq];
        v = fminf(v, __shfl_xor(v, 32, 64));
        v = fminf(v, __shfl_xor(v, 16, 64));
        if (lane < 16) pk[w][qq][lane] = v;
    }
    __syncthreads();                          // barrier 1: pk + cnt + stages visible

    // h==0 waves: 11th smallest of 64 chunk minima -> tau for group
    if (h == 0) {
        float md[KNN + 1];
#pragma unroll
        for (int s = 0; s <= KNN; ++s) md[s] = F32_INF;
        const int qsel = lane & 15;           // 4-way replicated
#pragma unroll
        for (int cc = 0; cc < 64; ++cc) {
            float d = pk[g * 4 + (cc >> 4)][qsel][cc & 15];
#pragma unroll
            for (int u = 0; u <= KNN; ++u) {
                const float lo = fminf(md[u], d);
                d = fmaxf(md[u], d);
                md[u] = lo;
            }
        }
        if (lane < 16) tau_s[lq_base + lane] = md[KNN] + 1e-3f;
    }
    __syncthreads();                          // barrier 2: tau visible

    float taum[Q];
    {
        const float tv = tau_s[lq_base + (lane & 15)];
#pragma unroll
        for (int qq = 0; qq < Q; ++qq) taum[qq] = rl(tv, qq);   // -> SGPRs
    }

    // ---------------- pass 2: collect hits incl. self (rare) ----------------
    float4 cp2 = pb[cb0 + lane];
    int jcur = cb0 + lane;
    for (int ti = 0; ti < NPTS / 4 / 64; ++ti) {
        const float4 np = (ti < NPTS / 4 / 64 - 1) ? pb[cb0 + (ti + 1) * 64 + lane] : cp2;
        const float a2x = -2.0f * cp2.x;
        const float a2y = -2.0f * cp2.y;
        const float a2z = -2.0f * cp2.z;
        const float aw  = cp2.w;
#pragma unroll
        for (int qq = 0; qq < Q; ++qq) {
            const float v = fmaf(a2x, qxs[qq], fmaf(a2y, qys[qq], fmaf(a2z, qzs[qq], aw)));
            if (__builtin_expect(v <= taum[qq], 0)) {
                const float px = -0.5f * a2x;
                const float py = -0.5f * a2y;
                const float pz = -0.5f * a2z;
                const float dot = fmaf(pz, qzs[qq], fmaf(py, qys[qq], px * qxs[qq]));
                const float d2 = fmaf(-2.0f, dot, qss[qq] + aw);
                const unsigned int fb = __float_as_uint(d2);
                const unsigned int m =
                    fb ^ ((unsigned int)((int)fb >> 31) | 0x80000000u);  // monotone
                const unsigned long long key =
                    ((unsigned long long)m << 13) | (unsigned long long)(unsigned)jcur;
                const int slot = atomicAdd(&cnt[lq_base + qq], 1);
                if (slot < CAP) coll[slot][lq_base + qq] = key;
            }
        }
        cp2 = np; jcur += 64;
    }
    __syncthreads();

    // ---------------- phase 3: top-11 bubble, filter self, indices -> LDS ----
    if (t < 32) {
        const int m = cnt[t];
        int mc = m;
#pragma unroll
        for (int off = 1; off < 32; off <<= 1)        // 32 active lanes only
            mc = max(mc, __shfl_xor(mc, off, 64));
        mc = __builtin_amdgcn_readfirstlane(mc);

        const int n = (bx & 255) * 32 + t;    // this lane's batch-local query

        unsigned long long md[KNN + 1];
#pragma unroll
        for (int s = 0; s <= KNN; ++s) md[s] = ~0ULL;

        if (mc <= CAP) {
            for (int cc = 0; cc < mc; ++cc) {
                unsigned long long key = (cc < m) ? coll[cc][t] : ~0ULL;
#pragma unroll
                for (int u = 0; u <= KNN; ++u) {
                    const bool lt = key < md[u];
                    const unsigned long long lo = lt ? key : md[u];
                    key = lt ? md[u] : key;
                    md[u] = lo;
                }
            }
        } else {
            const float4 qv = pb[n];
            for (int j = 0; j < NPTS; ++j) {
                const float4 p = pb[j];
                const float dot = fmaf(p.z, qv.z, fmaf(p.y, qv.y, p.x * qv.x));
                const float d2 = fmaf(-2.0f, dot, qv.w + p.w);
                const unsigned int fb = __float_as_uint(d2);
                const unsigned int mm =
                    fb ^ ((unsigned int)((int)fb >> 31) | 0x80000000u);
                unsigned long long key =
                    ((unsigned long long)mm << 13) | (unsigned long long)j;
                key = (j == n) ? ~0ULL : key;
#pragma unroll
                for (int u = 0; u <= KNN; ++u) {
                    const bool lt = key < md[u];
                    const unsigned long long lo = lt ? key : md[u];
                    key = lt ? md[u] : key;
                    md[u] = lo;
                }
            }
        }

        int outc = 0;
#pragma unroll
        for (int u = 0; u <= KNN; ++u) {
            const int idx = (int)(md[u] & 8191u);
            if (outc < KNN && idx != n) idx_s[t][outc++] = idx;
        }
    }
    __syncthreads();                          // barrier 4: idx_s visible

    // ================= FEAT + MLP (verbatim R14 math, 4 thr/point) ==========
    const int pl   = t >> 2;                  // point slot 0..31 (t<128)
    const int subh = t & 1;                   // hidden half
    const int subf = (t >> 1) & 1;            // feature half
    const int n_f  = (bx & 255) * 32 + pl;    // batch-local point

    if (t < 128 && (t & 3) == 0) {            // one lane per quad builds
        const float4 cq = pb[n_f];
        const float cx = cq.x, cy = cq.y, cz = cq.z;

        float nx[KNN], ny[KNN], nz[KNN];
#pragma unroll
        for (int k = 0; k < KNN; ++k) {
            const int j = idx_s[pl][k];
            const float4 p = pb[j];
            nx[k] = p.x; ny[k] = p.y; nz[k] = p.z;
        }

        float* fr = fs[pl];
        fr[0] = cx; fr[1] = cy; fr[2] = cz;
#pragma unroll
        for (int k = 0; k < KNN; ++k) {
            fr[3 + 3 * k + 0] = nx[k];
            fr[3 + 3 * k + 1] = ny[k];
            fr[3 + 3 * k + 2] = nz[k];
        }
#pragma unroll
        for (int k = 0; k < KNN; ++k) {
            fr[33 + 3 * k + 0] = nx[k] - cx;
            fr[33 + 3 * k + 1] = ny[k] - cy;
            fr[33 + 3 * k + 2] = nz[k] - cz;
        }
#pragma unroll
        for (int k = 0; k < KNN; ++k) {
            const float rx = nx[k] - cx, ry = ny[k] - cy, rz = nz[k] - cz;
            fr[63 + k] = sqrtf(fmaf(rz, rz, fmaf(ry, ry, rx * rx)));
        }

        float mx = 0.f, my = 0.f, mz = 0.f;
#pragma unroll
        for (int k = 0; k < KNN; ++k) { mx += nx[k]; my += ny[k]; mz += nz[k]; }
        mx *= (1.0f / KNN); my *= (1.0f / KNN); mz *= (1.0f / KNN);
        float c00 = 0.f, c01 = 0.f, c02 = 0.f, c11 = 0.f, c12 = 0.f, c22 = 0.f;
#pragma unroll
        for (int k = 0; k < KNN; ++k) {
            const float ex = nx[k] - mx, ey = ny[k] - my, ez = nz[k] - mz;
            c00 = fmaf(ex, ex, c00); c01 = fmaf(ex, ey, c01); c02 = fmaf(ex, ez, c02);
            c11 = fmaf(ey, ey, c11); c12 = fmaf(ey, ez, c12); c22 = fmaf(ez, ez, c22);
        }
        const float sc = 1.0f / (KNN - 1);
        c00 *= sc; c01 *= sc; c02 *= sc; c11 *= sc; c12 *= sc; c22 *= sc;

        // fp32 closed-form symmetric 3x3 eigenvalues
        const float qd = (c00 + c11 + c22) * (1.0f / 3.0f);
        const float pp1 = c01 * c01 + c02 * c02 + c12 * c12;
        const float d00 = c00 - qd, d11 = c11 - qd, d22 = c22 - qd;
        const float p2 = d00 * d00 + d11 * d11 + d22 * d22 + 2.0f * pp1;
        float l1, l2, l3;
        if (p2 < 1e-30f) {
            l1 = l2 = l3 = qd;
        } else {
            const float p = sqrtf(p2 * (1.0f / 6.0f));
            const float inv = 1.0f / p;
            const float e00 = d00 * inv, e11 = d11 * inv, e22 = d22 * inv;
            const float e01 = c01 * inv, e02 = c02 * inv, e12 = c12 * inv;
            float detB = e00 * (e11 * e22 - e12 * e12)
                       - e01 * (e01 * e22 - e12 * e02)
                       + e02 * (e01 * e12 - e11 * e02);
            float r = 0.5f * detB;
            r = fminf(1.0f, fmaxf(-1.0f, r));
            const float phi = acosf(r) * (1.0f / 3.0f);
            l1 = qd + 2.0f * p * __cosf(phi);                          // largest
            l3 = qd + 2.0f * p * __cosf(phi + 2.0943951023931953f);    // smallest
            l2 = 3.0f * qd - l1 - l3;
        }
        fr[73] = (l1 - l2) / l1;
        fr[74] = (l2 - l3) / l1;
        fr[75] = l3 / l1;
    }

    __syncthreads();   // barrier 5 (all 512 threads): features visible

    if (t < 128) {
        const float* fr = fs[pl];
        const int f0 = subf * 38;

        float hreg[32];
#pragma unroll
        for (int j = 0; j < 32; ++j) hreg[j] = (subf == 0) ? b1s[subh * 32 + j] : 0.0f;

#pragma unroll 2
        for (int ff = 0; ff < 38; ++ff) {
            const int f = f0 + ff;
            const float v = fr[f];
            // W1 read directly from global: row-major [76][64], L1-resident
            const float4* w4 = reinterpret_cast<const float4*>(W1 + f * HID + subh * 32);
#pragma unroll
            for (int j4 = 0; j4 < 8; ++j4) {
                const float4 wv = w4[j4];
                hreg[4 * j4 + 0] = fmaf(v, wv.x, hreg[4 * j4 + 0]);
                hreg[4 * j4 + 1] = fmaf(v, wv.y, hreg[4 * j4 + 1]);
                hreg[4 * j4 + 2] = fmaf(v, wv.z, hreg[4 * j4 + 2]);
                hreg[4 * j4 + 3] = fmaf(v, wv.w, hreg[4 * j4 + 3]);
            }
        }

        // combine feature halves (lanes differing in bit 1)
#pragma unroll
        for (int j = 0; j < 32; ++j) hreg[j] += __shfl_xor(hreg[j], 2, 64);

        float o0 = 0.f, o1 = 0.f, o2 = 0.f;
#pragma unroll
        for (int j = 0; j < 32; ++j) {
            const float r = fmaxf(hreg[j], 0.0f);
            const int jj = subh * 32 + j;
            o0 = fmaf(r, w2s[jj * 3 + 0], o0);
            o1 = fmaf(r, w2s[jj * 3 + 1], o1);
            o2 = fmaf(r, w2s[jj * 3 + 2], o2);
        }
        // combine hidden halves (lanes differing in bit 0)
        o0 += __shfl_xor(o0, 1, 64);
        o1 += __shfl_xor(o1, 1, 64);
        o2 += __shfl_xor(o2, 1, 64);

        if ((t & 3) == 0) {
            float* op = out + ((size_t)b * NPTS + n_f) * 3;
            op[0] = fmaxf(o0 + b2s[0], 0.0f);
            op[1] = fmaxf(o1 + b2s[1], 0.0f);
            op[2] = fmaxf(o2 + b2s[2], 0.0f);
        }
    }
}

extern "C" void kernel_launch(void* const* d_in, const int* in_sizes, int n_in,
                              void* d_out, int out_size, void* d_ws, size_t ws_size,
                              hipStream_t stream) {
    const float* cloud = (const float*)d_in[0];   // [4,8192,3]
    const float* W1    = (const float*)d_in[1];   // [76,64]
    const float* b1    = (const float*)d_in[2];   // [64]
    const float* W2    = (const float*)d_in[3];   // [64,3]
    const float* b2    = (const float*)d_in[4];   // [3]
    float* out = (float*)d_out;                   // [4,8192,3]

    float4* pts4 = (float4*)d_ws;                 // 512 KB

    prep_kernel<<<dim3(128), dim3(256), 0, stream>>>(cloud, pts4);
    knn_feat_kernel<<<dim3(1024), dim3(512), 0, stream>>>(pts4, W1, b1, W2, b2, out);
}

// Round 18
// 172.786 us; speedup vs baseline: 1.2188x; 1.2188x over previous
//
#include <hip/hip_runtime.h>
#include <math.h>

#define KNN    10
#define NPTS   8192
#define HID    64
#define NF     76
#define Q      16                // queries per wave
#define CAP    64                // pass-2 collection capacity per query
#define F32_INF __uint_as_float(0x7F800000u)

__device__ __forceinline__ float rl(float v, int lane) {
    return __int_as_float(__builtin_amdgcn_readlane(__float_as_int(v), lane));
}

// ---------------------------------------------------------------------------
// KNN — R14 scan (best measured: 113.6us, absmax 4.39e-3) with prep deleted:
// w = fmaf(z,z,fmaf(y,y,x*x)) computed INLINE from cloud — the exact prep
// expression, so every v / tau / key bit matches the validated chain.
// Tile loads: 3 dwords/lane (768 contiguous B per wave) instead of pts4
// dwordx4; scan is not BW-bound (25 GB/s), instr delta amortized /16.
// Block 512 thr = 8 waves = 2 query-groups x 4 candidate-quarters; grid 1024.
// ---------------------------------------------------------------------------
__global__ __launch_bounds__(512) void knn_kernel(const float* __restrict__ cloud,
                                                  unsigned short* __restrict__ knn_idx) {
    __shared__ unsigned long long coll[CAP][33];   // 16.9 KB
    __shared__ float pk[8][Q][17];                 // 8.7 KB
    __shared__ float tau_s[32];
    __shared__ int   cnt[32];

    const int t    = threadIdx.x;
    const int w    = t >> 6;                  // wave 0..7
    const int lane = t & 63;
    const int g    = w >> 2;                  // query group 0..1
    const int h    = w & 3;                   // candidate quarter 0..3
    const int bx   = blockIdx.x;              // 0..1023
    const int b    = bx >> 8;                 // batch
    const int n_base = (bx & 255) * 32 + g * Q;   // batch-local first query of group
    const int lq_base = g * Q;                // block-local query base
    const int cb0 = h * (NPTS / 4);           // candidate base for this wave

    const float* cb = cloud + (size_t)b * NPTS * 3;

    if (t < 32) cnt[t] = 0;                   // visible after barrier 1

    float qxs[Q], qys[Q], qzs[Q], qss[Q];
#pragma unroll
    for (int qq = 0; qq < Q; ++qq) {
        const float qx = cb[(n_base + qq) * 3 + 0];
        const float qy = cb[(n_base + qq) * 3 + 1];
        const float qz = cb[(n_base + qq) * 3 + 2];
        qxs[qq] = qx; qys[qq] = qy; qzs[qq] = qz;
        qss[qq] = fmaf(qz, qz, fmaf(qy, qy, qx * qx));   // prep's exact expr
    }

    // ---------------- pass 1: per-lane minima over this quarter ----------------
    float vmin[Q];
#pragma unroll
    for (int qq = 0; qq < Q; ++qq) vmin[qq] = F32_INF;

    float cx0 = cb[(cb0 + lane) * 3 + 0];
    float cy0 = cb[(cb0 + lane) * 3 + 1];
    float cz0 = cb[(cb0 + lane) * 3 + 2];
    for (int ti = 0; ti < NPTS / 4 / 64; ++ti) {  // 32 tiles
        float nx0 = cx0, ny0 = cy0, nz0 = cz0;
        if (ti < NPTS / 4 / 64 - 1) {
            const int c1 = cb0 + (ti + 1) * 64 + lane;
            nx0 = cb[c1 * 3 + 0]; ny0 = cb[c1 * 3 + 1]; nz0 = cb[c1 * 3 + 2];
        }
        const float aw  = fmaf(cz0, cz0, fmaf(cy0, cy0, cx0 * cx0));  // prep expr
        const float a2x = -2.0f * cx0;
        const float a2y = -2.0f * cy0;
        const float a2z = -2.0f * cz0;
#pragma unroll
        for (int qq = 0; qq < Q; ++qq) {
            const float v = fmaf(a2x, qxs[qq], fmaf(a2y, qys[qq], fmaf(a2z, qzs[qq], aw)));
            vmin[qq] = fminf(vmin[qq], v);    // self included (rank arg handles it)
        }
        cx0 = nx0; cy0 = ny0; cz0 = nz0;
    }

#pragma unroll
    for (int qq = 0; qq < Q; ++qq) {
        float v = vmin[qq];
        v = fminf(v, __shfl_xor(v, 32, 64));
        v = fminf(v, __shfl_xor(v, 16, 64));
        if (lane < 16) pk[w][qq][lane] = v;
    }
    __syncthreads();                          // barrier 1: pk + cnt visible

    // h==0 waves: 11th smallest of 64 chunk minima -> tau for group
    if (h == 0) {
        float md[KNN + 1];
#pragma unroll
        for (int s = 0; s <= KNN; ++s) md[s] = F32_INF;
        const int qsel = lane & 15;           // 4-way replicated
#pragma unroll
        for (int cc = 0; cc < 64; ++cc) {
            float d = pk[g * 4 + (cc >> 4)][qsel][cc & 15];
#pragma unroll
            for (int u = 0; u <= KNN; ++u) {
                const float lo = fminf(md[u], d);
                d = fmaxf(md[u], d);
                md[u] = lo;
            }
        }
        if (lane < 16) tau_s[lq_base + lane] = md[KNN] + 1e-3f;
    }
    __syncthreads();                          // barrier 2: tau visible

    float taum[Q];
    {
        const float tv = tau_s[lq_base + (lane & 15)];
#pragma unroll
        for (int qq = 0; qq < Q; ++qq) taum[qq] = rl(tv, qq);   // -> SGPRs
    }

    // ---------------- pass 2: collect hits incl. self (rare) ----------------
    float cx2 = cb[(cb0 + lane) * 3 + 0];
    float cy2 = cb[(cb0 + lane) * 3 + 1];
    float cz2 = cb[(cb0 + lane) * 3 + 2];
    int jcur = cb0 + lane;
    for (int ti = 0; ti < NPTS / 4 / 64; ++ti) {
        float nx2 = cx2, ny2 = cy2, nz2 = cz2;
        if (ti < NPTS / 4 / 64 - 1) {
            const int c1 = cb0 + (ti + 1) * 64 + lane;
            nx2 = cb[c1 * 3 + 0]; ny2 = cb[c1 * 3 + 1]; nz2 = cb[c1 * 3 + 2];
        }
        const float aw  = fmaf(cz2, cz2, fmaf(cy2, cy2, cx2 * cx2));
        const float a2x = -2.0f * cx2;
        const float a2y = -2.0f * cy2;
        const float a2z = -2.0f * cz2;
#pragma unroll
        for (int qq = 0; qq < Q; ++qq) {
            const float v = fmaf(a2x, qxs[qq], fmaf(a2y, qys[qq], fmaf(a2z, qzs[qq], aw)));
            if (__builtin_expect(v <= taum[qq], 0)) {
                // EXACT key: R1-chain d2 expression (px==cx2 bitwise)
                const float dot = fmaf(cz2, qzs[qq], fmaf(cy2, qys[qq], cx2 * qxs[qq]));
                const float d2 = fmaf(-2.0f, dot, qss[qq] + aw);
                const unsigned int fb = __float_as_uint(d2);
                const unsigned int m =
                    fb ^ ((unsigned int)((int)fb >> 31) | 0x80000000u);  // monotone
                const unsigned long long key =
                    ((unsigned long long)m << 13) | (unsigned long long)(unsigned)jcur;
                const int slot = atomicAdd(&cnt[lq_base + qq], 1);
                if (slot < CAP) coll[slot][lq_base + qq] = key;
            }
        }
        cx2 = nx2; cy2 = ny2; cz2 = nz2;
        jcur += 64;
    }
    __syncthreads();

    // ---------------- phase 3: top-11 bubble, filter self by index ----------
    if (t < 32) {
        const int m = cnt[t];
        int mc = m;
#pragma unroll
        for (int off = 1; off < 32; off <<= 1)        // 32 active lanes only
            mc = max(mc, __shfl_xor(mc, off, 64));
        mc = __builtin_amdgcn_readfirstlane(mc);

        const int n = (bx & 255) * 32 + t;    // this lane's batch-local query

        unsigned long long md[KNN + 1];
#pragma unroll
        for (int s = 0; s <= KNN; ++s) md[s] = ~0ULL;

        if (mc <= CAP) {
            for (int cc = 0; cc < mc; ++cc) {
                unsigned long long key = (cc < m) ? coll[cc][t] : ~0ULL;
#pragma unroll
                for (int u = 0; u <= KNN; ++u) {
                    const bool lt = key < md[u];
                    const unsigned long long lo = lt ? key : md[u];
                    key = lt ? md[u] : key;
                    md[u] = lo;
                }
            }
        } else {
            // exact serial fallback (never expected): full rescan, inline w
            const float qx = cb[n * 3 + 0];
            const float qy = cb[n * 3 + 1];
            const float qz = cb[n * 3 + 2];
            const float qs = fmaf(qz, qz, fmaf(qy, qy, qx * qx));
            for (int j = 0; j < NPTS; ++j) {
                const float px = cb[j * 3 + 0];
                const float py = cb[j * 3 + 1];
                const float pz = cb[j * 3 + 2];
                const float pw = fmaf(pz, pz, fmaf(py, py, px * px));
                const float dot = fmaf(pz, qz, fmaf(py, qy, px * qx));
                const float d2 = fmaf(-2.0f, dot, qs + pw);
                const unsigned int fb = __float_as_uint(d2);
                const unsigned int mm =
                    fb ^ ((unsigned int)((int)fb >> 31) | 0x80000000u);
                unsigned long long key =
                    ((unsigned long long)mm << 13) | (unsigned long long)j;
                key = (j == n) ? ~0ULL : key;
#pragma unroll
                for (int u = 0; u <= KNN; ++u) {
                    const bool lt = key < md[u];
                    const unsigned long long lo = lt ? key : md[u];
                    key = lt ? md[u] : key;
                    md[u] = lo;
                }
            }
        }

        unsigned short* outp = knn_idx + ((size_t)b * NPTS + n) * KNN;
        int outc = 0;
#pragma unroll
        for (int u = 0; u <= KNN; ++u) {
            const int idx = (int)(md[u] & 8191u);
            if (outc < KNN && idx != n) outp[outc++] = (unsigned short)idx;
        }
    }
}

// ---------------------------------------------------------------------------
// Features + MLP — R12/R14 best-measured config (4 thr/point, fp32 eigen,
// 256-thr blocks, grid 512), reading xyz directly from cloud (same float
// values as pts4 — prep deleted).
// ---------------------------------------------------------------------------
__global__ __launch_bounds__(256) void feat_mlp_kernel(const float* __restrict__ cloud,
                                                       const float* __restrict__ W1,
                                                       const float* __restrict__ b1,
                                                       const float* __restrict__ W2,
                                                       const float* __restrict__ b2,
                                                       const unsigned short* __restrict__ knn_idx,
                                                       float* __restrict__ out) {
    __shared__ float w1s[NF * 68];            // padded stride
    __shared__ float b1s[HID];
    __shared__ float w2s[HID * 3];
    __shared__ float b2s[3];
    __shared__ float fs[64][NF + 1];          // stride 77

    const int t = threadIdx.x;
    for (int idx = t; idx < NF * HID; idx += 256)
        w1s[(idx >> 6) * 68 + (idx & 63)] = W1[idx];
    if (t < HID) b1s[t] = b1[t];
    if (t < HID * 3) w2s[t] = W2[t];
    if (t < 3) b2s[t] = b2[t];

    const int pl   = t >> 2;                  // point slot 0..63
    const int subh = t & 1;                   // hidden half
    const int subf = (t >> 1) & 1;            // feature half
    const int gid = blockIdx.x * 64 + pl;     // 0..32767
    const int b = gid >> 13;
    const int n = gid & (NPTS - 1);
    const float* cb = cloud + (size_t)b * NPTS * 3;

    if ((t & 3) == 0) {                       // one lane per quad builds
        const float cx = cb[n * 3 + 0];
        const float cy = cb[n * 3 + 1];
        const float cz = cb[n * 3 + 2];

        float nx[KNN], ny[KNN], nz[KNN];
        const unsigned short* ki = knn_idx + (size_t)gid * KNN;
#pragma unroll
        for (int k = 0; k < KNN; ++k) {
            const int j = ki[k];
            nx[k] = cb[j * 3 + 0];
            ny[k] = cb[j * 3 + 1];
            nz[k] = cb[j * 3 + 2];
        }

        float* fr = fs[pl];
        fr[0] = cx; fr[1] = cy; fr[2] = cz;
#pragma unroll
        for (int k = 0; k < KNN; ++k) {
            fr[3 + 3 * k + 0] = nx[k];
            fr[3 + 3 * k + 1] = ny[k];
            fr[3 + 3 * k + 2] = nz[k];
        }
#pragma unroll
        for (int k = 0; k < KNN; ++k) {
            fr[33 + 3 * k + 0] = nx[k] - cx;
            fr[33 + 3 * k + 1] = ny[k] - cy;
            fr[33 + 3 * k + 2] = nz[k] - cz;
        }
#pragma unroll
        for (int k = 0; k < KNN; ++k) {
            const float rx = nx[k] - cx, ry = ny[k] - cy, rz = nz[k] - cz;
            fr[63 + k] = sqrtf(fmaf(rz, rz, fmaf(ry, ry, rx * rx)));
        }

        float mx = 0.f, my = 0.f, mz = 0.f;
#pragma unroll
        for (int k = 0; k < KNN; ++k) { mx += nx[k]; my += ny[k]; mz += nz[k]; }
        mx *= (1.0f / KNN); my *= (1.0f / KNN); mz *= (1.0f / KNN);
        float c00 = 0.f, c01 = 0.f, c02 = 0.f, c11 = 0.f, c12 = 0.f, c22 = 0.f;
#pragma unroll
        for (int k = 0; k < KNN; ++k) {
            const float ex = nx[k] - mx, ey = ny[k] - my, ez = nz[k] - mz;
            c00 = fmaf(ex, ex, c00); c01 = fmaf(ex, ey, c01); c02 = fmaf(ex, ez, c02);
            c11 = fmaf(ey, ey, c11); c12 = fmaf(ey, ez, c12); c22 = fmaf(ez, ez, c22);
        }
        const float sc = 1.0f / (KNN - 1);
        c00 *= sc; c01 *= sc; c02 *= sc; c11 *= sc; c12 *= sc; c22 *= sc;

        // fp32 closed-form symmetric 3x3 eigenvalues
        const float qd = (c00 + c11 + c22) * (1.0f / 3.0f);
        const float pp1 = c01 * c01 + c02 * c02 + c12 * c12;
        const float d00 = c00 - qd, d11 = c11 - qd, d22 = c22 - qd;
        const float p2 = d00 * d00 + d11 * d11 + d22 * d22 + 2.0f * pp1;
        float l1, l2, l3;
        if (p2 < 1e-30f) {
            l1 = l2 = l3 = qd;
        } else {
            const float p = sqrtf(p2 * (1.0f / 6.0f));
            const float inv = 1.0f / p;
            const float e00 = d00 * inv, e11 = d11 * inv, e22 = d22 * inv;
            const float e01 = c01 * inv, e02 = c02 * inv, e12 = c12 * inv;
            float detB = e00 * (e11 * e22 - e12 * e12)
                       - e01 * (e01 * e22 - e12 * e02)
                       + e02 * (e01 * e12 - e11 * e02);
            float r = 0.5f * detB;
            r = fminf(1.0f, fmaxf(-1.0f, r));
            const float phi = acosf(r) * (1.0f / 3.0f);
            l1 = qd + 2.0f * p * __cosf(phi);                          // largest
            l3 = qd + 2.0f * p * __cosf(phi + 2.0943951023931953f);    // smallest
            l2 = 3.0f * qd - l1 - l3;
        }
        fr[73] = (l1 - l2) / l1;
        fr[74] = (l2 - l3) / l1;
        fr[75] = l3 / l1;
    }

    __syncthreads();   // weights + features visible

    const float* fr = fs[pl];
    const int f0 = subf * 38;

    float h[32];
#pragma unroll
    for (int j = 0; j < 32; ++j) h[j] = (subf == 0) ? b1s[subh * 32 + j] : 0.0f;

#pragma unroll 2
    for (int ff = 0; ff < 38; ++ff) {
        const int f = f0 + ff;
        const float v = fr[f];
        const float4* w4 = reinterpret_cast<const float4*>(w1s + f * 68 + subh * 32);
#pragma unroll
        for (int j4 = 0; j4 < 8; ++j4) {
            const float4 w = w4[j4];
            h[4 * j4 + 0] = fmaf(v, w.x, h[4 * j4 + 0]);
            h[4 * j4 + 1] = fmaf(v, w.y, h[4 * j4 + 1]);
            h[4 * j4 + 2] = fmaf(v, w.z, h[4 * j4 + 2]);
            h[4 * j4 + 3] = fmaf(v, w.w, h[4 * j4 + 3]);
        }
    }

    // combine feature halves (lanes differing in bit 1)
#pragma unroll
    for (int j = 0; j < 32; ++j) h[j] += __shfl_xor(h[j], 2, 64);

    float o0 = 0.f, o1 = 0.f, o2 = 0.f;
#pragma unroll
    for (int j = 0; j < 32; ++j) {
        const float r = fmaxf(h[j], 0.0f);
        const int jj = subh * 32 + j;
        o0 = fmaf(r, w2s[jj * 3 + 0], o0);
        o1 = fmaf(r, w2s[jj * 3 + 1], o1);
        o2 = fmaf(r, w2s[jj * 3 + 2], o2);
    }
    // combine hidden halves (lanes differing in bit 0)
    o0 += __shfl_xor(o0, 1, 64);
    o1 += __shfl_xor(o1, 1, 64);
    o2 += __shfl_xor(o2, 1, 64);

    if ((t & 3) == 0) {
        float* op = out + (size_t)gid * 3;
        op[0] = fmaxf(o0 + b2s[0], 0.0f);
        op[1] = fmaxf(o1 + b2s[1], 0.0f);
        op[2] = fmaxf(o2 + b2s[2], 0.0f);
    }
}

extern "C" void kernel_launch(void* const* d_in, const int* in_sizes, int n_in,
                              void* d_out, int out_size, void* d_ws, size_t ws_size,
                              hipStream_t stream) {
    const float* cloud = (const float*)d_in[0];   // [4,8192,3]
    const float* W1    = (const float*)d_in[1];   // [76,64]
    const float* b1    = (const float*)d_in[2];   // [64]
    const float* W2    = (const float*)d_in[3];   // [64,3]
    const float* b2    = (const float*)d_in[4];   // [3]
    float* out = (float*)d_out;                   // [4,8192,3]

    unsigned short* knn = (unsigned short*)d_ws;  // 640 KB

    knn_kernel<<<dim3(1024), dim3(512), 0, stream>>>(cloud, knn);
    feat_mlp_kernel<<<dim3(512), dim3(256), 0, stream>>>(cloud, W1, b1, W2, b2, knn, out);
}

// Round 19
// 172.244 us; speedup vs baseline: 1.2226x; 1.0031x over previous
//
#include <hip/hip_runtime.h>
#include <math.h>

#define KNN    10
#define NPTS   8192
#define HID    64
#define NF     76
#define Q      16                // queries per wave
#define CAP    64                // pass-2 collection capacity per query
#define F32_INF __uint_as_float(0x7F800000u)

__device__ __forceinline__ float rl(float v, int lane) {
    return __int_as_float(__builtin_amdgcn_readlane(__float_as_int(v), lane));
}

// ---------------------------------------------------------------------------
// KNN — frozen R18 kernel (best measured: 112.3us, absmax 4.39e-3, selection
// chain validated 10 rounds). Inline w from cloud, transposed scan, rank-11
// chunk-minima threshold + 1e-3, exact R1-chain key rebuild, top-11 + filter.
// ---------------------------------------------------------------------------
__global__ __launch_bounds__(512) void knn_kernel(const float* __restrict__ cloud,
                                                  unsigned short* __restrict__ knn_idx) {
    __shared__ unsigned long long coll[CAP][33];   // 16.9 KB
    __shared__ float pk[8][Q][17];                 // 8.7 KB
    __shared__ float tau_s[32];
    __shared__ int   cnt[32];

    const int t    = threadIdx.x;
    const int w    = t >> 6;                  // wave 0..7
    const int lane = t & 63;
    const int g    = w >> 2;                  // query group 0..1
    const int h    = w & 3;                   // candidate quarter 0..3
    const int bx   = blockIdx.x;              // 0..1023
    const int b    = bx >> 8;                 // batch
    const int n_base = (bx & 255) * 32 + g * Q;   // batch-local first query of group
    const int lq_base = g * Q;                // block-local query base
    const int cb0 = h * (NPTS / 4);           // candidate base for this wave

    const float* cb = cloud + (size_t)b * NPTS * 3;

    if (t < 32) cnt[t] = 0;                   // visible after barrier 1

    float qxs[Q], qys[Q], qzs[Q], qss[Q];
#pragma unroll
    for (int qq = 0; qq < Q; ++qq) {
        const float qx = cb[(n_base + qq) * 3 + 0];
        const float qy = cb[(n_base + qq) * 3 + 1];
        const float qz = cb[(n_base + qq) * 3 + 2];
        qxs[qq] = qx; qys[qq] = qy; qzs[qq] = qz;
        qss[qq] = fmaf(qz, qz, fmaf(qy, qy, qx * qx));   // prep's exact expr
    }

    // ---------------- pass 1: per-lane minima over this quarter ----------------
    float vmin[Q];
#pragma unroll
    for (int qq = 0; qq < Q; ++qq) vmin[qq] = F32_INF;

    float cx0 = cb[(cb0 + lane) * 3 + 0];
    float cy0 = cb[(cb0 + lane) * 3 + 1];
    float cz0 = cb[(cb0 + lane) * 3 + 2];
    for (int ti = 0; ti < NPTS / 4 / 64; ++ti) {  // 32 tiles
        float nx0 = cx0, ny0 = cy0, nz0 = cz0;
        if (ti < NPTS / 4 / 64 - 1) {
            const int c1 = cb0 + (ti + 1) * 64 + lane;
            nx0 = cb[c1 * 3 + 0]; ny0 = cb[c1 * 3 + 1]; nz0 = cb[c1 * 3 + 2];
        }
        const float aw  = fmaf(cz0, cz0, fmaf(cy0, cy0, cx0 * cx0));  // prep expr
        const float a2x = -2.0f * cx0;
        const float a2y = -2.0f * cy0;
        const float a2z = -2.0f * cz0;
#pragma unroll
        for (int qq = 0; qq < Q; ++qq) {
            const float v = fmaf(a2x, qxs[qq], fmaf(a2y, qys[qq], fmaf(a2z, qzs[qq], aw)));
            vmin[qq] = fminf(vmin[qq], v);    // self included (rank arg handles it)
        }
        cx0 = nx0; cy0 = ny0; cz0 = nz0;
    }

#pragma unroll
    for (int qq = 0; qq < Q; ++qq) {
        float v = vmin[qq];
        v = fminf(v, __shfl_xor(v, 32, 64));
        v = fminf(v, __shfl_xor(v, 16, 64));
        if (lane < 16) pk[w][qq][lane] = v;
    }
    __syncthreads();                          // barrier 1: pk + cnt visible

    // h==0 waves: 11th smallest of 64 chunk minima -> tau for group
    if (h == 0) {
        float md[KNN + 1];
#pragma unroll
        for (int s = 0; s <= KNN; ++s) md[s] = F32_INF;
        const int qsel = lane & 15;           // 4-way replicated
#pragma unroll
        for (int cc = 0; cc < 64; ++cc) {
            float d = pk[g * 4 + (cc >> 4)][qsel][cc & 15];
#pragma unroll
            for (int u = 0; u <= KNN; ++u) {
                const float lo = fminf(md[u], d);
                d = fmaxf(md[u], d);
                md[u] = lo;
            }
        }
        if (lane < 16) tau_s[lq_base + lane] = md[KNN] + 1e-3f;
    }
    __syncthreads();                          // barrier 2: tau visible

    float taum[Q];
    {
        const float tv = tau_s[lq_base + (lane & 15)];
#pragma unroll
        for (int qq = 0; qq < Q; ++qq) taum[qq] = rl(tv, qq);   // -> SGPRs
    }

    // ---------------- pass 2: collect hits incl. self (rare) ----------------
    float cx2 = cb[(cb0 + lane) * 3 + 0];
    float cy2 = cb[(cb0 + lane) * 3 + 1];
    float cz2 = cb[(cb0 + lane) * 3 + 2];
    int jcur = cb0 + lane;
    for (int ti = 0; ti < NPTS / 4 / 64; ++ti) {
        float nx2 = cx2, ny2 = cy2, nz2 = cz2;
        if (ti < NPTS / 4 / 64 - 1) {
            const int c1 = cb0 + (ti + 1) * 64 + lane;
            nx2 = cb[c1 * 3 + 0]; ny2 = cb[c1 * 3 + 1]; nz2 = cb[c1 * 3 + 2];
        }
        const float aw  = fmaf(cz2, cz2, fmaf(cy2, cy2, cx2 * cx2));
        const float a2x = -2.0f * cx2;
        const float a2y = -2.0f * cy2;
        const float a2z = -2.0f * cz2;
#pragma unroll
        for (int qq = 0; qq < Q; ++qq) {
            const float v = fmaf(a2x, qxs[qq], fmaf(a2y, qys[qq], fmaf(a2z, qzs[qq], aw)));
            if (__builtin_expect(v <= taum[qq], 0)) {
                // EXACT key: R1-chain d2 expression
                const float dot = fmaf(cz2, qzs[qq], fmaf(cy2, qys[qq], cx2 * qxs[qq]));
                const float d2 = fmaf(-2.0f, dot, qss[qq] + aw);
                const unsigned int fb = __float_as_uint(d2);
                const unsigned int m =
                    fb ^ ((unsigned int)((int)fb >> 31) | 0x80000000u);  // monotone
                const unsigned long long key =
                    ((unsigned long long)m << 13) | (unsigned long long)(unsigned)jcur;
                const int slot = atomicAdd(&cnt[lq_base + qq], 1);
                if (slot < CAP) coll[slot][lq_base + qq] = key;
            }
        }
        cx2 = nx2; cy2 = ny2; cz2 = nz2;
        jcur += 64;
    }
    __syncthreads();

    // ---------------- phase 3: top-11 bubble, filter self by index ----------
    if (t < 32) {
        const int m = cnt[t];
        int mc = m;
#pragma unroll
        for (int off = 1; off < 32; off <<= 1)        // 32 active lanes only
            mc = max(mc, __shfl_xor(mc, off, 64));
        mc = __builtin_amdgcn_readfirstlane(mc);

        const int n = (bx & 255) * 32 + t;    // this lane's batch-local query

        unsigned long long md[KNN + 1];
#pragma unroll
        for (int s = 0; s <= KNN; ++s) md[s] = ~0ULL;

        if (mc <= CAP) {
            for (int cc = 0; cc < mc; ++cc) {
                unsigned long long key = (cc < m) ? coll[cc][t] : ~0ULL;
#pragma unroll
                for (int u = 0; u <= KNN; ++u) {
                    const bool lt = key < md[u];
                    const unsigned long long lo = lt ? key : md[u];
                    key = lt ? md[u] : key;
                    md[u] = lo;
                }
            }
        } else {
            // exact serial fallback (never expected): full rescan, inline w
            const float qx = cb[n * 3 + 0];
            const float qy = cb[n * 3 + 1];
            const float qz = cb[n * 3 + 2];
            const float qs = fmaf(qz, qz, fmaf(qy, qy, qx * qx));
            for (int j = 0; j < NPTS; ++j) {
                const float px = cb[j * 3 + 0];
                const float py = cb[j * 3 + 1];
                const float pz = cb[j * 3 + 2];
                const float pw = fmaf(pz, pz, fmaf(py, py, px * px));
                const float dot = fmaf(pz, qz, fmaf(py, qy, px * qx));
                const float d2 = fmaf(-2.0f, dot, qs + pw);
                const unsigned int fb = __float_as_uint(d2);
                const unsigned int mm =
                    fb ^ ((unsigned int)((int)fb >> 31) | 0x80000000u);
                unsigned long long key =
                    ((unsigned long long)mm << 13) | (unsigned long long)j;
                key = (j == n) ? ~0ULL : key;
#pragma unroll
                for (int u = 0; u <= KNN; ++u) {
                    const bool lt = key < md[u];
                    const unsigned long long lo = lt ? key : md[u];
                    key = lt ? md[u] : key;
                    md[u] = lo;
                }
            }
        }

        unsigned short* outp = knn_idx + ((size_t)b * NPTS + n) * KNN;
        int outc = 0;
#pragma unroll
        for (int u = 0; u <= KNN; ++u) {
            const int idx = (int)(md[u] & 8191u);
            if (outc < KNN && idx != n) outp[outc++] = (unsigned short)idx;
        }
    }
}

// ---------------------------------------------------------------------------
// Features + MLP — R18 config with QUAD-PARALLEL feature build (R19 change):
// the build previously ran on 1 of 4 lanes (10 serial gathers + cov + eigen
// = the longest unhidden chain at 2 waves/SIMD). Now lanes own 3/3/2/2
// neighbors (gather depth 10->3, same total fr LDS writes, just spread);
// mean/cov via quad partial sums + shfl_xor(1,2) reduces (~18 added shfl ops
// vs ~304 ds_read_b128/thread — negligible DS add, unlike R13's butterfly).
// Eigen redundant on all 4 lanes (same wave time), lane 0 writes.
// Tree-summed mean/cov: R13 used this pattern, absmax bit-identical.
// MLP part unchanged (best-measured R12/R14 layout).
// ---------------------------------------------------------------------------
__global__ __launch_bounds__(256) void feat_mlp_kernel(const float* __restrict__ cloud,
                                                       const float* __restrict__ W1,
                                                       const float* __restrict__ b1,
                                                       const float* __restrict__ W2,
                                                       const float* __restrict__ b2,
                                                       const unsigned short* __restrict__ knn_idx,
                                                       float* __restrict__ out) {
    __shared__ float w1s[NF * 68];            // padded stride
    __shared__ float b1s[HID];
    __shared__ float w2s[HID * 3];
    __shared__ float b2s[3];
    __shared__ float fs[64][NF + 1];          // stride 77

    const int t = threadIdx.x;
    for (int idx = t; idx < NF * HID; idx += 256)
        w1s[(idx >> 6) * 68 + (idx & 63)] = W1[idx];
    if (t < HID) b1s[t] = b1[t];
    if (t < HID * 3) w2s[t] = W2[t];
    if (t < 3) b2s[t] = b2[t];

    const int pl   = t >> 2;                  // point slot 0..63
    const int s    = t & 3;                   // quad sub-lane
    const int subh = t & 1;                   // hidden half
    const int subf = (t >> 1) & 1;            // feature half
    const int gid = blockIdx.x * 64 + pl;     // 0..32767
    const int b = gid >> 13;
    const int n = gid & (NPTS - 1);
    const float* cb = cloud + (size_t)b * NPTS * 3;

    // ---- quad-parallel feature build ----
    {
        const float cx = cb[n * 3 + 0];       // same addr across quad (broadcast)
        const float cy = cb[n * 3 + 1];
        const float cz = cb[n * 3 + 2];

        // neighbor ownership: s=0:{0,1,2} s=1:{3,4,5} s=2:{6,7} s=3:{8,9}
        const int kbase = (s == 0) ? 0 : (s == 1) ? 3 : (s == 2) ? 6 : 8;
        const int kcnt  = (s < 2) ? 3 : 2;

        float nx[3], ny[3], nz[3];
        const unsigned short* ki = knn_idx + (size_t)gid * KNN;
        for (int kk = 0; kk < kcnt; ++kk) {
            const int j = ki[kbase + kk];
            nx[kk] = cb[j * 3 + 0];
            ny[kk] = cb[j * 3 + 1];
            nz[kk] = cb[j * 3 + 2];
        }

        float* fr = fs[pl];
        if (s == 0) { fr[0] = cx; fr[1] = cy; fr[2] = cz; }
        for (int kk = 0; kk < kcnt; ++kk) {
            const int k = kbase + kk;
            fr[3 + 3 * k + 0] = nx[kk];
            fr[3 + 3 * k + 1] = ny[kk];
            fr[3 + 3 * k + 2] = nz[kk];
            const float rx = nx[kk] - cx, ry = ny[kk] - cy, rz = nz[kk] - cz;
            fr[33 + 3 * k + 0] = rx;
            fr[33 + 3 * k + 1] = ry;
            fr[33 + 3 * k + 2] = rz;
            fr[63 + k] = sqrtf(fmaf(rz, rz, fmaf(ry, ry, rx * rx)));
        }

        // quad-reduced mean
        float smx = 0.f, smy = 0.f, smz = 0.f;
        for (int kk = 0; kk < kcnt; ++kk) { smx += nx[kk]; smy += ny[kk]; smz += nz[kk]; }
#define QSUM(v) { v += __shfl_xor(v, 1, 64); v += __shfl_xor(v, 2, 64); }
        QSUM(smx); QSUM(smy); QSUM(smz);
        const float mx = smx * (1.0f / KNN);
        const float my = smy * (1.0f / KNN);
        const float mz = smz * (1.0f / KNN);

        // quad-reduced covariance partials
        float c00 = 0.f, c01 = 0.f, c02 = 0.f, c11 = 0.f, c12 = 0.f, c22 = 0.f;
        for (int kk = 0; kk < kcnt; ++kk) {
            const float ex = nx[kk] - mx, ey = ny[kk] - my, ez = nz[kk] - mz;
            c00 = fmaf(ex, ex, c00); c01 = fmaf(ex, ey, c01); c02 = fmaf(ex, ez, c02);
            c11 = fmaf(ey, ey, c11); c12 = fmaf(ey, ez, c12); c22 = fmaf(ez, ez, c22);
        }
        QSUM(c00); QSUM(c01); QSUM(c02); QSUM(c11); QSUM(c12); QSUM(c22);
#undef QSUM
        const float sc = 1.0f / (KNN - 1);
        c00 *= sc; c01 *= sc; c02 *= sc; c11 *= sc; c12 *= sc; c22 *= sc;

        // fp32 closed-form symmetric 3x3 eigenvalues (all 4 lanes, same time)
        const float qd = (c00 + c11 + c22) * (1.0f / 3.0f);
        const float pp1 = c01 * c01 + c02 * c02 + c12 * c12;
        const float d00 = c00 - qd, d11 = c11 - qd, d22 = c22 - qd;
        const float p2 = d00 * d00 + d11 * d11 + d22 * d22 + 2.0f * pp1;
        float l1, l2, l3;
        if (p2 < 1e-30f) {
            l1 = l2 = l3 = qd;
        } else {
            const float p = sqrtf(p2 * (1.0f / 6.0f));
            const float inv = 1.0f / p;
            const float e00 = d00 * inv, e11 = d11 * inv, e22 = d22 * inv;
            const float e01 = c01 * inv, e02 = c02 * inv, e12 = c12 * inv;
            float detB = e00 * (e11 * e22 - e12 * e12)
                       - e01 * (e01 * e22 - e12 * e02)
                       + e02 * (e01 * e12 - e11 * e02);
            float r = 0.5f * detB;
            r = fminf(1.0f, fmaxf(-1.0f, r));
            const float phi = acosf(r) * (1.0f / 3.0f);
            l1 = qd + 2.0f * p * __cosf(phi);                          // largest
            l3 = qd + 2.0f * p * __cosf(phi + 2.0943951023931953f);    // smallest
            l2 = 3.0f * qd - l1 - l3;
        }
        if (s == 0) {
            fr[73] = (l1 - l2) / l1;
            fr[74] = (l2 - l3) / l1;
            fr[75] = l3 / l1;
        }
    }

    __syncthreads();   // weights + features visible

    const float* fr = fs[pl];
    const int f0 = subf * 38;

    float h[32];
#pragma unroll
    for (int j = 0; j < 32; ++j) h[j] = (subf == 0) ? b1s[subh * 32 + j] : 0.0f;

#pragma unroll 2
    for (int ff = 0; ff < 38; ++ff) {
        const int f = f0 + ff;
        const float v = fr[f];
        const float4* w4 = reinterpret_cast<const float4*>(w1s + f * 68 + subh * 32);
#pragma unroll
        for (int j4 = 0; j4 < 8; ++j4) {
            const float4 w = w4[j4];
            h[4 * j4 + 0] = fmaf(v, w.x, h[4 * j4 + 0]);
            h[4 * j4 + 1] = fmaf(v, w.y, h[4 * j4 + 1]);
            h[4 * j4 + 2] = fmaf(v, w.z, h[4 * j4 + 2]);
            h[4 * j4 + 3] = fmaf(v, w.w, h[4 * j4 + 3]);
        }
    }

    // combine feature halves (lanes differing in bit 1)
#pragma unroll
    for (int j = 0; j < 32; ++j) h[j] += __shfl_xor(h[j], 2, 64);

    float o0 = 0.f, o1 = 0.f, o2 = 0.f;
#pragma unroll
    for (int j = 0; j < 32; ++j) {
        const float r = fmaxf(h[j], 0.0f);
        const int jj = subh * 32 + j;
        o0 = fmaf(r, w2s[jj * 3 + 0], o0);
        o1 = fmaf(r, w2s[jj * 3 + 1], o1);
        o2 = fmaf(r, w2s[jj * 3 + 2], o2);
    }
    // combine hidden halves (lanes differing in bit 0)
    o0 += __shfl_xor(o0, 1, 64);
    o1 += __shfl_xor(o1, 1, 64);
    o2 += __shfl_xor(o2, 1, 64);

    if ((t & 3) == 0) {
        float* op = out + (size_t)gid * 3;
        op[0] = fmaxf(o0 + b2s[0], 0.0f);
        op[1] = fmaxf(o1 + b2s[1], 0.0f);
        op[2] = fmaxf(o2 + b2s[2], 0.0f);
    }
}

extern "C" void kernel_launch(void* const* d_in, const int* in_sizes, int n_in,
                              void* d_out, int out_size, void* d_ws, size_t ws_size,
                              hipStream_t stream) {
    const float* cloud = (const float*)d_in[0];   // [4,8192,3]
    const float* W1    = (const float*)d_in[1];   // [76,64]
    const float* b1    = (const float*)d_in[2];   // [64]
    const float* W2    = (const float*)d_in[3];   // [64,3]
    const float* b2    = (const float*)d_in[4];   // [3]
    float* out = (float*)d_out;                   // [4,8192,3]

    unsigned short* knn = (unsigned short*)d_ws;  // 640 KB

    knn_kernel<<<dim3(1024), dim3(512), 0, stream>>>(cloud, knn);
    feat_mlp_kernel<<<dim3(512), dim3(256), 0, stream>>>(cloud, W1, b1, W2, b2, knn, out);
}